// Round 1
// baseline (1309.994 us; speedup 1.0000x reference)
//
#include <hip/hip_runtime.h>

#define PPX  128
#define PP2  16384          // PPX*PPX
#define WINX 256
#define IMH  896
#define IMW  896
#define NB   24
#define NI   8
#define HP   (IMH + WINX)   // padded height 1152
#define WP   (IMW + WINX)

// ws layout (float units):
// [0..5]                    mu_p[3], sd_p[3]
// [8 .. 8+192*8)            per-box structs (8 floats each)
// [2048 .. 2048+192*512)    mask bitmaps (uint32 words, 512 per box)
// [102400 .. +8*PP2*3)      patch_bg buffers per image
#define WS_BOX  8
#define WS_MASK 2048
#define WS_PBG  102400

__global__ void copy_img_k(const float4* __restrict__ src, float4* __restrict__ dst, int n4) {
  int i = blockIdx.x * blockDim.x + threadIdx.x;
  int stride = gridDim.x * blockDim.x;
  for (; i < n4; i += stride) dst[i] = src[i];
}

__global__ void patch_stats_k(const float* __restrict__ patch, float* __restrict__ ws) {
  float s0=0,s1=0,s2=0,q0=0,q1=0,q2=0;
  for (int i = threadIdx.x; i < PP2; i += 256) {
    float a = patch[i*3+0], b = patch[i*3+1], c = patch[i*3+2];
    s0+=a; s1+=b; s2+=c; q0+=a*a; q1+=b*b; q2+=c*c;
  }
  __shared__ float red[256][6];
  red[threadIdx.x][0]=s0; red[threadIdx.x][1]=s1; red[threadIdx.x][2]=s2;
  red[threadIdx.x][3]=q0; red[threadIdx.x][4]=q1; red[threadIdx.x][5]=q2;
  __syncthreads();
  for (int s = 128; s > 0; s >>= 1) {
    if (threadIdx.x < s)
      for (int k=0;k<6;++k) red[threadIdx.x][k] += red[threadIdx.x+s][k];
    __syncthreads();
  }
  if (threadIdx.x == 0) {
    for (int c=0;c<3;++c) {
      float mu  = red[0][c]   * (1.0f/PP2);
      float var = red[0][3+c] * (1.0f/PP2) - mu*mu;
      float sd  = sqrtf(fmaxf(var, 0.f)) + 1e-6f;
      ws[c] = mu; ws[3+c] = sd;
    }
  }
}

// one block (256 threads) per (image, box)
__global__ void box_setup_k(const float* __restrict__ boxes,
                            const float* __restrict__ Wsc,
                            const float* __restrict__ bsc,
                            const float* __restrict__ Wg,
                            const float* __restrict__ bgv,
                            float* __restrict__ ws) {
  int bn = blockIdx.x;                 // b*NB + n
  const float* bx = boxes + bn*4;
  float ya = bx[0], xa = bx[1], yb = bx[2], xb = bx[3];
  float bh = (yb - ya) / (float)IMH;
  float bw = (xb - xa) / (float)IMW;
  float z  = bh*Wsc[0] + bw*Wsc[1] + bsc[0];
  float sig = 1.0f / (1.0f + expf(-z));
  float scale = sig * 0.4f;
  float h = yb - ya, w = xb - xa;
  float ps = floorf(sqrtf((h*w)*scale));
  float oy = ya + h*0.5f, ox = xa + w*0.5f;
  float ymp = fmaxf(oy - ps*0.5f, 0.0f);
  float xmp = fmaxf(ox - ps*0.5f, 0.0f);
  if (ymp + ps > (float)IMH) ymp = (float)IMH - ps;
  if (xmp + ps > (float)IMW) xmp = (float)IMW - ps;
  int yi = (int)ymp, xi = (int)xmp, ph = (int)ps;
  float valid = (ps > 60.0f) ? 1.0f : 0.0f;

  // mask bitmap + mean(sigmoid)
  unsigned int* mwords = ((unsigned int*)ws) + WS_MASK + bn*512;
  float lsum = 0.f;
  int lane = threadIdx.x & 63;
  for (int i = 0; i < 64; ++i) {
    int p = i*256 + threadIdx.x;
    float zz = bh*Wg[p] + bw*Wg[PP2 + p] + bgv[p];
    lsum += 1.0f / (1.0f + expf(-zz));
    unsigned long long m = __ballot(zz > 0.0f);
    if (lane == 0) {
      int base = p >> 5;  // even word index for this wave's 64 bits
      mwords[base]   = (unsigned int)(m & 0xffffffffULL);
      mwords[base+1] = (unsigned int)(m >> 32);
    }
  }
  __shared__ float red[256];
  red[threadIdx.x] = lsum;
  __syncthreads();
  for (int s = 128; s > 0; s >>= 1) {
    if (threadIdx.x < s) red[threadIdx.x] += red[threadIdx.x + s];
    __syncthreads();
  }
  if (threadIdx.x == 0) {
    float* bst = ws + WS_BOX + bn*8;
    bst[0] = scale;
    bst[1] = ps;
    ((int*)bst)[2] = yi;
    ((int*)bst)[3] = xi;
    ((int*)bst)[4] = ph;
    bst[5] = valid;
    bst[6] = red[0] * (1.0f/PP2);   // mask mean
    bst[7] = 0.f;
  }
}

// total loss, fully determined by precomputed per-box data
__global__ void loss_k(const float* __restrict__ ws, float* __restrict__ loss_out) {
  int b = threadIdx.x;
  float total = 0.f;
  if (b < NI) {
    float sum_s = 0.f, cnt = 0.f, bgl = 0.f;
    for (int n = 0; n < NB; ++n) {
      const float* bst = ws + WS_BOX + (b*NB + n)*8;
      float v = bst[5];
      sum_s += bst[0]*v; cnt += v; bgl += bst[6]*v;
    }
    float nn = fmaxf(cnt, 1.0f);
    float m = sum_s / nn;
    float var = 0.f;
    for (int n = 0; n < NB; ++n) {
      const float* bst = ws + WS_BOX + (b*NB + n)*8;
      float d = bst[0] - m;
      var += bst[5]*d*d;
    }
    var /= nn;
    total = bgl + m + 0.5f*var;
  }
  for (int off = 32; off; off >>= 1) total += __shfl_down(total, off);
  if (threadIdx.x == 0) *loss_out = total;
}

// one 1024-thread block per image; sequential over boxes
__global__ __launch_bounds__(1024) void paste_k(float* __restrict__ out,
                                                const float* __restrict__ patch,
                                                float* __restrict__ ws) {
  const int b = blockIdx.x;
  const int tid = threadIdx.x;
  __shared__ float s_alpha[3], s_beta[3];
  __shared__ float s_red[16][8];
  __shared__ unsigned int s_mask[512];
  float* __restrict__ pbg = ws + WS_PBG + (size_t)b*PP2*3;
  float* __restrict__ img = out + (size_t)b*IMH*IMW*3;

  for (int n = 0; n < NB; ++n) {
    const float* bst = ws + WS_BOX + (b*NB + n)*8;
    float valid = bst[5];
    if (valid < 0.5f) continue;                 // uniform across block
    int yi = ((const int*)bst)[2];
    int xi = ((const int*)bst)[3];
    int ph = ((const int*)bst)[4];
    float phf = (float)(ph > 1 ? ph : 1);

    const unsigned int* mwords = ((const unsigned int*)ws) + WS_MASK + (b*NB + n)*512;
    if (tid < 512) s_mask[tid] = mwords[tid];

    // ---- Phase A: crop background (bilinear from current image), stats ----
    float sm[3] = {0,0,0}, sq[3] = {0,0,0};
    for (int idx = tid; idx < PP2; idx += 1024) {
      int py = idx >> 7, px = idx & 127;
      float ys = ((float)yi + (py + 0.5f)*phf*(1.0f/PPX)) - 0.5f;
      float xs = ((float)xi + (px + 0.5f)*phf*(1.0f/PPX)) - 0.5f;
      ys = fminf(fmaxf(ys, 0.f), (float)(HP-1));
      xs = fminf(fmaxf(xs, 0.f), (float)(WP-1));
      float fy0 = floorf(ys), fx0 = floorf(xs);
      int y0 = (int)fy0, x0 = (int)fx0;
      int y1 = y0 + 1 < HP-1 ? y0 + 1 : HP-1;
      int x1 = x0 + 1 < WP-1 ? x0 + 1 : WP-1;
      float wy = ys - fy0, wx = xs - fx0;
      bool y0i = y0 < IMH, y1i = y1 < IMH, x0i = x0 < IMW, x1i = x1 < IMW;
      const float* r0 = img + (size_t)y0*IMW*3;
      const float* r1 = img + (size_t)y1*IMW*3;
      #pragma unroll
      for (int c = 0; c < 3; ++c) {
        float v00 = (y0i && x0i) ? r0[x0*3+c] : 0.f;
        float v01 = (y0i && x1i) ? r0[x1*3+c] : 0.f;
        float v10 = (y1i && x0i) ? r1[x0*3+c] : 0.f;
        float v11 = (y1i && x1i) ? r1[x1*3+c] : 0.f;
        float v = (1.f-wy)*((1.f-wx)*v00 + wx*v01) + wy*((1.f-wx)*v10 + wx*v11);
        pbg[idx*3+c] = v;
        sm[c] += v; sq[c] += v*v;
      }
    }
    // block-reduce 6 values
    float vals[6] = {sm[0],sm[1],sm[2],sq[0],sq[1],sq[2]};
    #pragma unroll
    for (int off = 32; off; off >>= 1)
      #pragma unroll
      for (int k = 0; k < 6; ++k) vals[k] += __shfl_down(vals[k], off);
    int wid = tid >> 6;
    if ((tid & 63) == 0)
      for (int k = 0; k < 6; ++k) s_red[wid][k] = vals[k];
    __syncthreads();
    if (tid == 0) {
      float acc[6] = {0,0,0,0,0,0};
      for (int w2 = 0; w2 < 16; ++w2)
        for (int k = 0; k < 6; ++k) acc[k] += s_red[w2][k];
      for (int c = 0; c < 3; ++c) {
        float mu  = acc[c]   * (1.0f/PP2);
        float var = acc[3+c] * (1.0f/PP2) - mu*mu;
        float sd  = sqrtf(fmaxf(var, 0.f)) + 1e-6f;
        float alpha = sd / ws[3+c];          // sd_b / sd_p
        s_alpha[c] = alpha;
        s_beta[c]  = mu - ws[c]*alpha;       // mu_b - mu_p*alpha
      }
    }
    __syncthreads();

    // ---- Phase B: resize blended into ph x ph and paste ----
    int tot = ph*ph;
    for (int idx = tid; idx < tot; idx += 1024) {
      int r = (int)((unsigned)idx / (unsigned)ph);
      int c = idx - r*ph;
      float sy = ((r + 0.5f)*128.0f)/phf - 0.5f;
      float sx = ((c + 0.5f)*128.0f)/phf - 0.5f;
      sy = fminf(fmaxf(sy, 0.f), 127.f);
      sx = fminf(fmaxf(sx, 0.f), 127.f);
      float fy0 = floorf(sy), fx0 = floorf(sx);
      int py0 = (int)fy0, px0 = (int)fx0;
      int py1 = py0 + 1 < 127 ? py0 + 1 : 127;
      int px1 = px0 + 1 < 127 ? px0 + 1 : 127;
      float wy = sy - fy0, wx = sx - fx0;
      int i00 = (py0<<7)+px0, i01 = (py0<<7)+px1, i10 = (py1<<7)+px0, i11 = (py1<<7)+px1;
      bool m00 = (s_mask[i00>>5] >> (i00&31)) & 1u;
      bool m01 = (s_mask[i01>>5] >> (i01&31)) & 1u;
      bool m10 = (s_mask[i10>>5] >> (i10&31)) & 1u;
      bool m11 = (s_mask[i11>>5] >> (i11&31)) & 1u;
      float* dst = img + ((size_t)(yi + r)*IMW + (xi + c))*3;
      #pragma unroll
      for (int ch = 0; ch < 3; ++ch) {
        float a = s_alpha[ch], be = s_beta[ch];
        float t00 = m00 ? patch[i00*3+ch]*a + be : pbg[i00*3+ch];
        float t01 = m01 ? patch[i01*3+ch]*a + be : pbg[i01*3+ch];
        float t10 = m10 ? patch[i10*3+ch]*a + be : pbg[i10*3+ch];
        float t11 = m11 ? patch[i11*3+ch]*a + be : pbg[i11*3+ch];
        float v = (1.f-wy)*((1.f-wx)*t00 + wx*t01) + wy*((1.f-wx)*t10 + wx*t11);
        dst[ch] = v;
      }
    }
    __syncthreads();   // next box's crop must see this paste
  }
}

extern "C" void kernel_launch(void* const* d_in, const int* in_sizes, int n_in,
                              void* d_out, int out_size, void* d_ws, size_t ws_size,
                              hipStream_t stream) {
  const float* boxes  = (const float*)d_in[0];
  const float* images = (const float*)d_in[1];
  const float* patch  = (const float*)d_in[2];
  const float* Wsc    = (const float*)d_in[3];
  const float* bsc    = (const float*)d_in[4];
  const float* Wg     = (const float*)d_in[5];
  const float* bgv    = (const float*)d_in[6];
  float* out = (float*)d_out;
  float* ws  = (float*)d_ws;

  int n4 = (NI*IMH*IMW*3) / 4;
  copy_img_k<<<2048, 256, 0, stream>>>((const float4*)images, (float4*)out, n4);
  patch_stats_k<<<1, 256, 0, stream>>>(patch, ws);
  box_setup_k<<<NI*NB, 256, 0, stream>>>(boxes, Wsc, bsc, Wg, bgv, ws);
  loss_k<<<1, 64, 0, stream>>>(ws, out + (size_t)NI*IMH*IMW*3);
  paste_k<<<NI, 1024, 0, stream>>>(out, patch, ws);
}

// Round 2
// 352.685 us; speedup vs baseline: 3.7143x; 3.7143x over previous
//
#include <hip/hip_runtime.h>

#define PPX  128
#define PP2  16384          // PPX*PPX
#define WINX 256
#define IMH  896
#define IMW  896
#define NB   24
#define NI   8
#define HP   (IMH + WINX)   // padded height 1152
#define WP   (IMW + WINX)
#define CB   32             // blocks per image per step kernel

// ws layout (float units):
// [0..5]                     mu_p[3], sd_p[3]
// [8 .. 8+192*8)             per-box structs (8 floats each)
// [2048 .. 2048+192*512)     mask bitmaps (uint32 words, 512 per box)
// [100352 .. 100352+8*32*6)  per-(image,block) partial stats for current step
// [102400 .. +8*PP2*3)       patch_bg buffers per image
#define WS_BOX  8
#define WS_MASK 2048
#define WS_PART 100352
#define WS_PBG  102400

__global__ void copy_img_k(const float4* __restrict__ src, float4* __restrict__ dst, int n4) {
  int i = blockIdx.x * blockDim.x + threadIdx.x;
  int stride = gridDim.x * blockDim.x;
  for (; i < n4; i += stride) dst[i] = src[i];
}

__global__ void patch_stats_k(const float* __restrict__ patch, float* __restrict__ ws) {
  float s0=0,s1=0,s2=0,q0=0,q1=0,q2=0;
  for (int i = threadIdx.x; i < PP2; i += 256) {
    float a = patch[i*3+0], b = patch[i*3+1], c = patch[i*3+2];
    s0+=a; s1+=b; s2+=c; q0+=a*a; q1+=b*b; q2+=c*c;
  }
  __shared__ float red[256][6];
  red[threadIdx.x][0]=s0; red[threadIdx.x][1]=s1; red[threadIdx.x][2]=s2;
  red[threadIdx.x][3]=q0; red[threadIdx.x][4]=q1; red[threadIdx.x][5]=q2;
  __syncthreads();
  for (int s = 128; s > 0; s >>= 1) {
    if (threadIdx.x < s)
      for (int k=0;k<6;++k) red[threadIdx.x][k] += red[threadIdx.x+s][k];
    __syncthreads();
  }
  if (threadIdx.x == 0) {
    for (int c=0;c<3;++c) {
      float mu  = red[0][c]   * (1.0f/PP2);
      float var = red[0][3+c] * (1.0f/PP2) - mu*mu;
      float sd  = sqrtf(fmaxf(var, 0.f)) + 1e-6f;
      ws[c] = mu; ws[3+c] = sd;
    }
  }
}

// one block (256 threads) per (image, box)
__global__ void box_setup_k(const float* __restrict__ boxes,
                            const float* __restrict__ Wsc,
                            const float* __restrict__ bsc,
                            const float* __restrict__ Wg,
                            const float* __restrict__ bgv,
                            float* __restrict__ ws) {
  int bn = blockIdx.x;                 // b*NB + n
  const float* bx = boxes + bn*4;
  float ya = bx[0], xa = bx[1], yb = bx[2], xb = bx[3];
  float bh = (yb - ya) / (float)IMH;
  float bw = (xb - xa) / (float)IMW;
  float z  = bh*Wsc[0] + bw*Wsc[1] + bsc[0];
  float sig = 1.0f / (1.0f + expf(-z));
  float scale = sig * 0.4f;
  float h = yb - ya, w = xb - xa;
  float ps = floorf(sqrtf((h*w)*scale));
  float oy = ya + h*0.5f, ox = xa + w*0.5f;
  float ymp = fmaxf(oy - ps*0.5f, 0.0f);
  float xmp = fmaxf(ox - ps*0.5f, 0.0f);
  if (ymp + ps > (float)IMH) ymp = (float)IMH - ps;
  if (xmp + ps > (float)IMW) xmp = (float)IMW - ps;
  int yi = (int)ymp, xi = (int)xmp, ph = (int)ps;
  float valid = (ps > 60.0f) ? 1.0f : 0.0f;

  // mask bitmap + mean(sigmoid)
  unsigned int* mwords = ((unsigned int*)ws) + WS_MASK + bn*512;
  float lsum = 0.f;
  int lane = threadIdx.x & 63;
  for (int i = 0; i < 64; ++i) {
    int p = i*256 + threadIdx.x;
    float zz = bh*Wg[p] + bw*Wg[PP2 + p] + bgv[p];
    lsum += 1.0f / (1.0f + expf(-zz));
    unsigned long long m = __ballot(zz > 0.0f);
    if (lane == 0) {
      int base = p >> 5;  // even word index for this wave's 64 bits
      mwords[base]   = (unsigned int)(m & 0xffffffffULL);
      mwords[base+1] = (unsigned int)(m >> 32);
    }
  }
  __shared__ float red[256];
  red[threadIdx.x] = lsum;
  __syncthreads();
  for (int s = 128; s > 0; s >>= 1) {
    if (threadIdx.x < s) red[threadIdx.x] += red[threadIdx.x + s];
    __syncthreads();
  }
  if (threadIdx.x == 0) {
    float* bst = ws + WS_BOX + bn*8;
    bst[0] = scale;
    bst[1] = ps;
    ((int*)bst)[2] = yi;
    ((int*)bst)[3] = xi;
    ((int*)bst)[4] = ph;
    bst[5] = valid;
    bst[6] = red[0] * (1.0f/PP2);   // mask mean
    bst[7] = 0.f;
  }
}

// total loss, fully determined by precomputed per-box data
__global__ void loss_k(const float* __restrict__ ws, float* __restrict__ loss_out) {
  int b = threadIdx.x;
  float total = 0.f;
  if (b < NI) {
    float sum_s = 0.f, cnt = 0.f, bgl = 0.f;
    for (int n = 0; n < NB; ++n) {
      const float* bst = ws + WS_BOX + (b*NB + n)*8;
      float v = bst[5];
      sum_s += bst[0]*v; cnt += v; bgl += bst[6]*v;
    }
    float nn = fmaxf(cnt, 1.0f);
    float m = sum_s / nn;
    float var = 0.f;
    for (int n = 0; n < NB; ++n) {
      const float* bst = ws + WS_BOX + (b*NB + n)*8;
      float d = bst[0] - m;
      var += bst[5]*d*d;
    }
    var /= nn;
    total = bgl + m + 0.5f*var;
  }
  for (int off = 32; off; off >>= 1) total += __shfl_down(total, off);
  if (threadIdx.x == 0) *loss_out = total;
}

// step kernel 1: crop current background for box n of every image.
// grid = NI*CB blocks x 256 threads; each block does 512 of the 16384 pixels.
__global__ __launch_bounds__(256) void crop_k(const float* __restrict__ out,
                                              float* __restrict__ ws, int n) {
  const int b   = blockIdx.x >> 5;    // / CB
  const int blk = blockIdx.x & (CB-1);
  const int tid = threadIdx.x;
  const float* bst = ws + WS_BOX + (b*NB + n)*8;
  if (bst[5] < 0.5f) return;
  const int yi = ((const int*)bst)[2];
  const int xi = ((const int*)bst)[3];
  const int ph = ((const int*)bst)[4];
  const float phf = (float)(ph > 1 ? ph : 1);
  const float* __restrict__ img = out + (size_t)b*IMH*IMW*3;
  float* __restrict__ pbg = ws + WS_PBG + (size_t)b*PP2*3;

  float sm[3] = {0,0,0}, sq[3] = {0,0,0};
  #pragma unroll
  for (int k = 0; k < 2; ++k) {
    int idx = blk*512 + k*256 + tid;
    int py = idx >> 7, px = idx & 127;
    float ys = ((float)yi + (py + 0.5f)*phf*(1.0f/PPX)) - 0.5f;
    float xs = ((float)xi + (px + 0.5f)*phf*(1.0f/PPX)) - 0.5f;
    ys = fminf(fmaxf(ys, 0.f), (float)(HP-1));
    xs = fminf(fmaxf(xs, 0.f), (float)(WP-1));
    float fy0 = floorf(ys), fx0 = floorf(xs);
    int y0 = (int)fy0, x0 = (int)fx0;
    int y1 = y0 + 1 < HP-1 ? y0 + 1 : HP-1;
    int x1 = x0 + 1 < WP-1 ? x0 + 1 : WP-1;
    float wy = ys - fy0, wx = xs - fx0;
    bool y0i = y0 < IMH, y1i = y1 < IMH, x0i = x0 < IMW, x1i = x1 < IMW;
    const float* r0 = img + (size_t)y0*IMW*3;
    const float* r1 = img + (size_t)y1*IMW*3;
    #pragma unroll
    for (int c = 0; c < 3; ++c) {
      float v00 = (y0i && x0i) ? r0[x0*3+c] : 0.f;
      float v01 = (y0i && x1i) ? r0[x1*3+c] : 0.f;
      float v10 = (y1i && x0i) ? r1[x0*3+c] : 0.f;
      float v11 = (y1i && x1i) ? r1[x1*3+c] : 0.f;
      float v = (1.f-wy)*((1.f-wx)*v00 + wx*v01) + wy*((1.f-wx)*v10 + wx*v11);
      pbg[idx*3+c] = v;
      sm[c] += v; sq[c] += v*v;
    }
  }
  float vals[6] = {sm[0],sm[1],sm[2],sq[0],sq[1],sq[2]};
  #pragma unroll
  for (int off = 32; off; off >>= 1)
    #pragma unroll
    for (int k = 0; k < 6; ++k) vals[k] += __shfl_down(vals[k], off);
  __shared__ float s_red[4][6];
  int wid = tid >> 6;
  if ((tid & 63) == 0)
    for (int k = 0; k < 6; ++k) s_red[wid][k] = vals[k];
  __syncthreads();
  if (tid == 0) {
    float* part = ws + WS_PART + (b*CB + blk)*6;
    for (int k = 0; k < 6; ++k)
      part[k] = s_red[0][k] + s_red[1][k] + s_red[2][k] + s_red[3][k];
  }
}

// step kernel 2: reduce stats (redundantly per block), blend+resize+paste box n.
__global__ __launch_bounds__(256) void paste_step_k(float* __restrict__ out,
                                                    const float* __restrict__ patch,
                                                    float* __restrict__ ws, int n) {
  const int b   = blockIdx.x >> 5;
  const int blk = blockIdx.x & (CB-1);
  const int tid = threadIdx.x;
  const float* bst = ws + WS_BOX + (b*NB + n)*8;
  if (bst[5] < 0.5f) return;
  const int yi = ((const int*)bst)[2];
  const int xi = ((const int*)bst)[3];
  const int ph = ((const int*)bst)[4];
  const float phf = (float)(ph > 1 ? ph : 1);
  float* __restrict__ img = out + (size_t)b*IMH*IMW*3;
  const float* __restrict__ pbg = ws + WS_PBG + (size_t)b*PP2*3;

  __shared__ float s_ab[6];            // alpha[3], beta[3]
  __shared__ unsigned int s_mask[512];
  {
    const unsigned int* mwords = ((const unsigned int*)ws) + WS_MASK + (b*NB + n)*512;
    s_mask[tid]       = mwords[tid];
    s_mask[tid + 256] = mwords[tid + 256];
  }
  if (tid < 32) {
    const float* part = ws + WS_PART + (b*CB + tid)*6;
    float v[6];
    #pragma unroll
    for (int k = 0; k < 6; ++k) v[k] = part[k];
    #pragma unroll
    for (int off = 16; off; off >>= 1)
      #pragma unroll
      for (int k = 0; k < 6; ++k) v[k] += __shfl_down(v[k], off, 32);
    if (tid == 0) {
      #pragma unroll
      for (int c = 0; c < 3; ++c) {
        float mu  = v[c]   * (1.0f/PP2);
        float var = v[3+c] * (1.0f/PP2) - mu*mu;
        float sd  = sqrtf(fmaxf(var, 0.f)) + 1e-6f;
        float alpha = sd / ws[3+c];          // sd_b / sd_p
        s_ab[c]   = alpha;
        s_ab[3+c] = mu - ws[c]*alpha;        // mu_b - mu_p*alpha
      }
    }
  }
  __syncthreads();

  const int tot = ph*ph;
  const int chunk = (tot + CB - 1) / CB;
  const int i0 = blk*chunk;
  const int i1 = min(tot, i0 + chunk);
  for (int idx = i0 + tid; idx < i1; idx += 256) {
    int r = (int)((unsigned)idx / (unsigned)ph);
    int c = idx - r*ph;
    float sy = ((r + 0.5f)*128.0f)/phf - 0.5f;
    float sx = ((c + 0.5f)*128.0f)/phf - 0.5f;
    sy = fminf(fmaxf(sy, 0.f), 127.f);
    sx = fminf(fmaxf(sx, 0.f), 127.f);
    float fy0 = floorf(sy), fx0 = floorf(sx);
    int py0 = (int)fy0, px0 = (int)fx0;
    int py1 = py0 + 1 < 127 ? py0 + 1 : 127;
    int px1 = px0 + 1 < 127 ? px0 + 1 : 127;
    float wy = sy - fy0, wx = sx - fx0;
    int i00 = (py0<<7)+px0, i01 = (py0<<7)+px1, i10 = (py1<<7)+px0, i11 = (py1<<7)+px1;
    bool m00 = (s_mask[i00>>5] >> (i00&31)) & 1u;
    bool m01 = (s_mask[i01>>5] >> (i01&31)) & 1u;
    bool m10 = (s_mask[i10>>5] >> (i10&31)) & 1u;
    bool m11 = (s_mask[i11>>5] >> (i11&31)) & 1u;
    float* dst = img + ((size_t)(yi + r)*IMW + (xi + c))*3;
    #pragma unroll
    for (int ch = 0; ch < 3; ++ch) {
      float a = s_ab[ch], be = s_ab[3+ch];
      float t00 = m00 ? patch[i00*3+ch]*a + be : pbg[i00*3+ch];
      float t01 = m01 ? patch[i01*3+ch]*a + be : pbg[i01*3+ch];
      float t10 = m10 ? patch[i10*3+ch]*a + be : pbg[i10*3+ch];
      float t11 = m11 ? patch[i11*3+ch]*a + be : pbg[i11*3+ch];
      float v = (1.f-wy)*((1.f-wx)*t00 + wx*t01) + wy*((1.f-wx)*t10 + wx*t11);
      dst[ch] = v;
    }
  }
}

extern "C" void kernel_launch(void* const* d_in, const int* in_sizes, int n_in,
                              void* d_out, int out_size, void* d_ws, size_t ws_size,
                              hipStream_t stream) {
  const float* boxes  = (const float*)d_in[0];
  const float* images = (const float*)d_in[1];
  const float* patch  = (const float*)d_in[2];
  const float* Wsc    = (const float*)d_in[3];
  const float* bsc    = (const float*)d_in[4];
  const float* Wg     = (const float*)d_in[5];
  const float* bgv    = (const float*)d_in[6];
  float* out = (float*)d_out;
  float* ws  = (float*)d_ws;

  int n4 = (NI*IMH*IMW*3) / 4;
  copy_img_k<<<2048, 256, 0, stream>>>((const float4*)images, (float4*)out, n4);
  patch_stats_k<<<1, 256, 0, stream>>>(patch, ws);
  box_setup_k<<<NI*NB, 256, 0, stream>>>(boxes, Wsc, bsc, Wg, bgv, ws);
  loss_k<<<1, 64, 0, stream>>>(ws, out + (size_t)NI*IMH*IMW*3);
  for (int n = 0; n < NB; ++n) {
    crop_k<<<NI*CB, 256, 0, stream>>>(out, ws, n);
    paste_step_k<<<NI*CB, 256, 0, stream>>>(out, patch, ws, n);
  }
}